// Round 7
// baseline (1532.155 us; speedup 1.0000x reference)
//
#include <hip/hip_runtime.h>
#include <math.h>

#define BB 4
#define LL 2048
#define DD 512
#define NH 8
#define DINNER 2048
#define NLAYERS 4
#define MM (BB * LL)  // 8192

typedef __attribute__((ext_vector_type(8))) __bf16 bf16x8;
typedef __attribute__((ext_vector_type(4))) float f32x4;
typedef __attribute__((ext_vector_type(4))) unsigned short us4;

__device__ __forceinline__ unsigned short f2b(float f) {
  union { float f; unsigned u; } v; v.f = f;
  unsigned r = v.u + 0x7fffu + ((v.u >> 16) & 1u);
  return (unsigned short)(r >> 16);
}
__device__ __forceinline__ float b2f(unsigned short h) {
  union { unsigned u; float f; } v; v.u = ((unsigned)h) << 16; return v.f;
}

__device__ __forceinline__ void gload16(const void* g, void* l) {
  __builtin_amdgcn_global_load_lds(
      (const __attribute__((address_space(1))) void*)g,
      (__attribute__((address_space(3))) void*)l, 16, 0, 0);
}

// ---------------- init: temporal enc + embedding gather ----------------
__global__ __launch_bounds__(512) void init_kernel(
    const int* __restrict__ etype, const float* __restrict__ etime,
    const float* __restrict__ npm, const float* __restrict__ emb,
    float* __restrict__ tem, float* __restrict__ x) {
  int row = blockIdx.x;
  int d = threadIdx.x;
  float t = etime[row];
  float mask = npm[row];
  int dd = d & ~1;
  float pv = expf(9.210340371976184f * ((float)dd * (1.0f / (float)DD)));
  float r = t / pv;
  float val = (d & 1) ? cosf(r) : sinf(r);
  tem[(size_t)row * DD + d] = val * mask;
  int ty = etype[row];
  x[(size_t)row * DD + d] = emb[(size_t)ty * DD + d];
}

// ---------------- x + tem -> fp32 + bf16 ----------------
__global__ __launch_bounds__(256) void add_tem_kernel(
    const float4* __restrict__ x, const float4* __restrict__ tem,
    float4* __restrict__ xa, us4* __restrict__ xab) {
  int i = blockIdx.x * 256 + threadIdx.x;
  float4 a = x[i], t = tem[i];
  float4 s = make_float4(a.x + t.x, a.y + t.y, a.z + t.z, a.w + t.w);
  xa[i] = s;
  us4 p = {f2b(s.x), f2b(s.y), f2b(s.z), f2b(s.w)};
  xab[i] = p;
}

// ---------------- weight transpose+convert: fp32 [K][N] -> bf16 [N][K] ----
__global__ __launch_bounds__(256) void wtrans_kernel(
    const float* __restrict__ in, unsigned short* __restrict__ out,
    int K, int N, long in_ls, long out_ls) {
  __shared__ float t[32][33];
  int l = blockIdx.z;
  int n0 = blockIdx.x * 32, k0 = blockIdx.y * 32;
  int tx = threadIdx.x & 31, ty = threadIdx.x >> 5;
  const float* ip = in + (size_t)l * in_ls;
  unsigned short* op = out + (size_t)l * out_ls;
#pragma unroll
  for (int r = ty; r < 32; r += 8)
    t[r][tx] = ip[(size_t)(k0 + r) * N + n0 + tx];
  __syncthreads();
#pragma unroll
  for (int r = ty; r < 32; r += 8)
    op[(size_t)(n0 + r) * K + k0 + tx] = f2b(t[tx][r]);
}

// ---- MFMA GEMM, 2-phase pipelined: C = A(bf16 [M,K]) @ WT(bf16 [N,K])^T --
template <int BM, bool BIAS, bool RES, bool GELU_, bool OBF16>
__global__ __launch_bounds__(256) void gemm_kernel(
    const unsigned short* __restrict__ A, const unsigned short* __restrict__ WT,
    const float* __restrict__ bias, const float* __restrict__ res, int ldres,
    void* __restrict__ Cv, int ldc, int M, int N, int K) {
  __shared__ unsigned short As[2][BM * 32];
  __shared__ unsigned short Bs[2][128 * 32];
  constexpr int NT = (BM == 128) ? 4 : 2;
  int tid = threadIdx.x;
  int w = tid >> 6, l = tid & 63;
  int li = l & 15, g = l >> 4;
  int row0 = blockIdx.y * BM, col0 = blockIdx.x * 128;
  int wm = (BM == 128) ? (w & 1) * 64 : 0;
  int wnb = (BM == 128) ? (w >> 1) * 64 : w * 32;
  f32x4 acc[4][NT];
#pragma unroll
  for (int i = 0; i < 4; i++)
#pragma unroll
    for (int j = 0; j < NT; j++) acc[i][j] = (f32x4){0.f, 0.f, 0.f, 0.f};

  int lr = l >> 2;
  int lc = (l & 3) ^ (lr & 3);

  auto stage = [&](int bb, int kb) {
    int k0 = kb * 32;
    if (BM == 128) {
#pragma unroll
      for (int i = 0; i < 2; i++) {
        int ai = w * 2 + i;
        gload16(A + (size_t)(row0 + ai * 16 + lr) * K + k0 + lc * 8,
                &As[bb][ai * 512]);
        gload16(WT + (size_t)(col0 + ai * 16 + lr) * K + k0 + lc * 8,
                &Bs[bb][ai * 512]);
      }
    } else {
      gload16(A + (size_t)(row0 + w * 16 + lr) * K + k0 + lc * 8,
              &As[bb][w * 512]);
#pragma unroll
      for (int i = 0; i < 2; i++) {
        int bi = w * 2 + i;
        gload16(WT + (size_t)(col0 + bi * 16 + lr) * K + k0 + lc * 8,
                &Bs[bb][bi * 512]);
      }
    }
  };

  int nk = K >> 5;
  stage(0, 0);
  __syncthreads();
  int buf = 0;
  for (int kb = 0; kb < nk; kb++) {
    if (kb + 1 < nk) stage(buf ^ 1, kb + 1);
    bf16x8 af[4], bf_[NT];
#pragma unroll
    for (int mt = 0; mt < 4; mt++) {
      int r = wm + mt * 16 + li;
      af[mt] = *(const bf16x8*)&As[buf][r * 32 + ((g ^ (r & 3)) * 8)];
    }
#pragma unroll
    for (int nt = 0; nt < NT; nt++) {
      int r = wnb + nt * 16 + li;
      bf_[nt] = *(const bf16x8*)&Bs[buf][r * 32 + ((g ^ (r & 3)) * 8)];
    }
#pragma unroll
    for (int mt = 0; mt < 4; mt++)
#pragma unroll
      for (int nt = 0; nt < NT; nt++)
        acc[mt][nt] = __builtin_amdgcn_mfma_f32_16x16x32_bf16(
            af[mt], bf_[nt], acc[mt][nt], 0, 0, 0);
    __syncthreads();
    buf ^= 1;
  }
#pragma unroll
  for (int mt = 0; mt < 4; mt++) {
#pragma unroll
    for (int nt = 0; nt < NT; nt++) {
#pragma unroll
      for (int r = 0; r < 4; r++) {
        int row = row0 + wm + mt * 16 + g * 4 + r;
        int col = col0 + wnb + nt * 16 + li;
        float v = acc[mt][nt][r];
        if (BIAS) v += bias[col];
        if (RES) v += res[(size_t)row * ldres + col];
        if (GELU_) v = 0.5f * v * (1.0f + erff(v * 0.70710678118654752f));
        if (OBF16)
          ((unsigned short*)Cv)[(size_t)row * ldc + col] = f2b(v);
        else
          ((float*)Cv)[(size_t)row * ldc + col] = v;
      }
    }
  }
}

// ---------------- transpose v slice of qkv -> vT [bh*64+d][L] ----------
__global__ __launch_bounds__(256) void vtrans_kernel(
    const unsigned short* __restrict__ qkv, unsigned short* __restrict__ vT) {
  __shared__ unsigned short t[64][65];
  int bh = blockIdx.y;
  int b = bh >> 3, h = bh & 7;
  int l0 = blockIdx.x * 64;
  int tid = threadIdx.x;
  int c = tid & 63, p = tid >> 6;
#pragma unroll
  for (int r = p; r < 64; r += 4)
    t[r][c] = qkv[(size_t)(b * LL + l0 + r) * 1536 + 1024 + h * 64 + c];
  __syncthreads();
#pragma unroll
  for (int r = p; r < 64; r += 4)
    vT[((size_t)bh * 64 + r) * LL + l0 + c] = t[c][r];
}

// ---------------- meanV over L per (b,h,d), from vT ----------------
__global__ __launch_bounds__(256) void meanv_kernel(
    const unsigned short* __restrict__ vT, float* __restrict__ meanV) {
  __shared__ float red[256];
  int bh = blockIdx.x;
  int tid = threadIdx.x;
  int d = tid >> 2, p = tid & 3;
  const unsigned short* vp = vT + ((size_t)bh * 64 + d) * LL;
  float s = 0.f;
  for (int i = p * 512; i < p * 512 + 512; i++) s += b2f(vp[i]);
  red[tid] = s;
  __syncthreads();
  if (p == 0)
    meanV[bh * 64 + d] =
        (red[tid] + red[tid + 1] + red[tid + 2] + red[tid + 3]) *
        (1.0f / (float)LL);
}

// ---------------- MFMA flash attention (v5: reg-prefetch, barrier-free) ----
// Grid 1024 = 32 bh x 32 qtiles, LPT + XCD-chunked remap. 4 independent waves,
// each owns 16 q-rows. K tile (128 keys) lives in REGISTERS, prefetched one
// tile ahead (issued right after current QK where old set dies). Pad mask is
// a per-block LDS bias table (built once). Wave-private P repack LDS. No
// per-tile barriers -> no vmcnt(0) drains, waves self-pace.
__global__ __launch_bounds__(256, 2) void attn_kernel(
    const unsigned short* __restrict__ qkv, const unsigned short* __restrict__ vT,
    const int* __restrict__ etype, const float* __restrict__ meanV,
    unsigned short* __restrict__ ao) {
  __shared__ float biasL[LL];                // 8 KB pad bias
  __shared__ unsigned short Ps[4][16][136];  // 17.4 KB wave-private
  int hwbid = blockIdx.x;
  int work = (hwbid & 7) * 128 + (hwbid >> 3);
  int bh = work >> 5;
  int qt = 31 - (work & 31);  // LPT: big blocks first
  int h = bh & 7, b = bh >> 3;
  int q0 = qt * 64;
  int tid = threadIdx.x, w = tid >> 6, l = tid & 63;
  int g = l >> 4, li = l & 15;

  // pad-bias table: bias[key] = -1e9 if PAD else 0
#pragma unroll
  for (int e = 0; e < 8; e++) {
    int key = e * 256 + tid;
    biasL[key] = (etype[b * LL + key] == 0) ? -1.0e9f : 0.f;
  }

  const unsigned short* qrp =
      qkv + (size_t)(b * LL + q0 + w * 16 + li) * 1536 + h * 64;
  bf16x8 aq0 = *(const bf16x8*)&qrp[g * 8];
  bf16x8 aq1 = *(const bf16x8*)&qrp[32 + g * 8];

  const unsigned short* kbase =
      qkv + (size_t)(b * LL + li) * 1536 + 512 + h * 64;
  const unsigned short* vbase = vT + ((size_t)(bh * 64 + li)) * LL;

  __syncthreads();  // biasL ready (only barrier in the kernel)

  f32x4 o[4];
#pragma unroll
  for (int n = 0; n < 4; n++) o[n] = (f32x4){0.f, 0.f, 0.f, 0.f};
  float mreg[4], lreg[4];
#pragma unroll
  for (int r = 0; r < 4; r++) { mreg[r] = -3.0e38f; lreg[r] = 0.f; }

  int nt = (qt + 2) >> 1;  // number of 128-key tiles

  bf16x8 kA[8], kB[8], kC[8], kD[8];
  auto ldK = [&](int k0, bf16x8 (&ka)[8], bf16x8 (&kb)[8]) {
#pragma unroll
    for (int n = 0; n < 8; n++) {
      const unsigned short* kp = kbase + (size_t)(k0 + n * 16) * 1536;
      ka[n] = *(const bf16x8*)&kp[g * 8];
      kb[n] = *(const bf16x8*)&kp[32 + g * 8];
    }
  };
  ldK(0, kA, kB);  // prologue

  auto tile = [&](int j, bf16x8 (&ca)[8], bf16x8 (&cb)[8],
                  bf16x8 (&na)[8], bf16x8 (&nb)[8]) {
    int k0 = j << 7;
    // QK^T from current K registers (no wait: loaded a full tile ago)
    f32x4 s[8];
    __builtin_amdgcn_s_setprio(1);
#pragma unroll
    for (int n = 0; n < 8; n++) {
      f32x4 a = (f32x4){0.f, 0.f, 0.f, 0.f};
      a = __builtin_amdgcn_mfma_f32_16x16x32_bf16(aq0, ca[n], a, 0, 0, 0);
      a = __builtin_amdgcn_mfma_f32_16x16x32_bf16(aq1, cb[n], a, 0, 0, 0);
      s[n] = a;
    }
    __builtin_amdgcn_s_setprio(0);
    // prefetch next K tile into the other register set (ca/cb now dead)
    if (j + 1 < nt) ldK(k0 + 128, na, nb);
    // V frags for k-slots 0,1 (latency hidden under softmax)
    bf16x8 bva[4], bvb[4];
#pragma unroll
    for (int n = 0; n < 4; n++) {
      const unsigned short* vp = vbase + (size_t)(n * 16) * LL + k0;
      bva[n] = *(const bf16x8*)&vp[g * 8];
      bvb[n] = *(const bf16x8*)&vp[32 + g * 8];
    }
    // pad bias (broadcast LDS reads) + scale + causal mask
    float bias8[8];
#pragma unroll
    for (int n = 0; n < 8; n++) bias8[n] = biasL[k0 + n * 16 + li];
#pragma unroll
    for (int n = 0; n < 8; n++) {
      int key = k0 + n * 16 + li;
#pragma unroll
      for (int r = 0; r < 4; r++) {
        int qrow = q0 + w * 16 + g * 4 + r;
        float sv = s[n][r] * 0.125f + bias8[n];
        if (key > qrow) sv = -1.0e9f;
        s[n][r] = sv;
      }
    }
    // wave-parallel online softmax (reduce across the 16 li lanes)
    float pm[4], corr[4], psum[4];
#pragma unroll
    for (int r = 0; r < 4; r++) {
      float m0 = fmaxf(fmaxf(s[0][r], s[1][r]), fmaxf(s[2][r], s[3][r]));
      float m1 = fmaxf(fmaxf(s[4][r], s[5][r]), fmaxf(s[6][r], s[7][r]));
      pm[r] = fmaxf(m0, m1);
    }
#pragma unroll
    for (int msk = 1; msk <= 8; msk <<= 1)
#pragma unroll
      for (int r = 0; r < 4; r++)
        pm[r] = fmaxf(pm[r], __shfl_xor(pm[r], msk, 64));
#pragma unroll
    for (int r = 0; r < 4; r++) {
      float mnew = fmaxf(mreg[r], pm[r]);
      corr[r] = __expf(mreg[r] - mnew);
      mreg[r] = mnew;
      float ps = 0.f;
#pragma unroll
      for (int n = 0; n < 8; n++) {
        float p = __expf(s[n][r] - mnew);
        s[n][r] = p;
        ps += p;
      }
      psum[r] = ps;
    }
#pragma unroll
    for (int msk = 1; msk <= 8; msk <<= 1)
#pragma unroll
      for (int r = 0; r < 4; r++) psum[r] += __shfl_xor(psum[r], msk, 64);
#pragma unroll
    for (int r = 0; r < 4; r++) lreg[r] = lreg[r] * corr[r] + psum[r];
    // P -> wave-private LDS (same-wave write->read ordered by lgkmcnt)
#pragma unroll
    for (int n = 0; n < 8; n++)
#pragma unroll
      for (int r = 0; r < 4; r++)
        Ps[w][g * 4 + r][n * 16 + li] = f2b(s[n][r]);
    // rescale O
#pragma unroll
    for (int n = 0; n < 4; n++)
#pragma unroll
      for (int r = 0; r < 4; r++) o[n][r] *= corr[r];
    // V frags for k-slots 2,3
    bf16x8 bvc[4], bvd[4];
#pragma unroll
    for (int n = 0; n < 4; n++) {
      const unsigned short* vp = vbase + (size_t)(n * 16) * LL + k0 + 64;
      bvc[n] = *(const bf16x8*)&vp[g * 8];
      bvd[n] = *(const bf16x8*)&vp[32 + g * 8];
    }
    // PV
    bf16x8 ap0 = *(const bf16x8*)&Ps[w][li][g * 8];
    bf16x8 ap1 = *(const bf16x8*)&Ps[w][li][32 + g * 8];
    bf16x8 ap2 = *(const bf16x8*)&Ps[w][li][64 + g * 8];
    bf16x8 ap3 = *(const bf16x8*)&Ps[w][li][96 + g * 8];
    __builtin_amdgcn_s_setprio(1);
#pragma unroll
    for (int n = 0; n < 4; n++)
      o[n] = __builtin_amdgcn_mfma_f32_16x16x32_bf16(ap0, bva[n], o[n], 0, 0, 0);
#pragma unroll
    for (int n = 0; n < 4; n++)
      o[n] = __builtin_amdgcn_mfma_f32_16x16x32_bf16(ap1, bvb[n], o[n], 0, 0, 0);
#pragma unroll
    for (int n = 0; n < 4; n++)
      o[n] = __builtin_amdgcn_mfma_f32_16x16x32_bf16(ap2, bvc[n], o[n], 0, 0, 0);
#pragma unroll
    for (int n = 0; n < 4; n++)
      o[n] = __builtin_amdgcn_mfma_f32_16x16x32_bf16(ap3, bvd[n], o[n], 0, 0, 0);
    __builtin_amdgcn_s_setprio(0);
  };

  for (int j = 0; j < nt; j += 2) {
    tile(j, kA, kB, kC, kD);
    if (j + 1 < nt) tile(j + 1, kC, kD, kA, kB);
  }

  // epilogue
#pragma unroll
  for (int r = 0; r < 4; r++) {
    int qr = q0 + w * 16 + g * 4 + r;
    float inv = 1.0f / lreg[r];
    bool dead = (mreg[r] <= -1.0e8f);
#pragma unroll
    for (int n = 0; n < 4; n++) {
      float v = dead ? meanV[bh * 64 + n * 16 + li] : o[n][r] * inv;
      ao[(size_t)(b * LL + qr) * DD + h * 64 + n * 16 + li] = f2b(v);
    }
  }
}

// ---------------- LayerNorm (+npm) -> fp32 + bf16 ----------------
__global__ __launch_bounds__(256) void ln_kernel(
    const float* __restrict__ in, const float* __restrict__ g,
    const float* __restrict__ bta, const float* __restrict__ npm,
    float* __restrict__ out, unsigned short* __restrict__ out_bf) {
  __shared__ float red[4];
  int row = blockIdx.x;
  int tid = threadIdx.x;
  const float* rp = in + (size_t)row * DD;
  float v0 = rp[tid], v1 = rp[tid + 256];
  float s = v0 + v1;
#pragma unroll
  for (int o = 32; o > 0; o >>= 1) s += __shfl_down(s, o, 64);
  if ((tid & 63) == 0) red[tid >> 6] = s;
  __syncthreads();
  float mean = (red[0] + red[1] + red[2] + red[3]) * (1.0f / (float)DD);
  float d0 = v0 - mean, d1 = v1 - mean;
  float sq = d0 * d0 + d1 * d1;
#pragma unroll
  for (int o = 32; o > 0; o >>= 1) sq += __shfl_down(sq, o, 64);
  __syncthreads();
  if ((tid & 63) == 0) red[tid >> 6] = sq;
  __syncthreads();
  float var = (red[0] + red[1] + red[2] + red[3]) * (1.0f / (float)DD);
  float rstd = rsqrtf(var + 1e-6f);
  float m = npm[row];
  float o0 = (d0 * rstd * g[tid] + bta[tid]) * m;
  float o1 = (d1 * rstd * g[tid + 256] + bta[tid + 256]) * m;
  out[(size_t)row * DD + tid] = o0;
  out[(size_t)row * DD + tid + 256] = o1;
  out_bf[(size_t)row * DD + tid] = f2b(o0);
  out_bf[(size_t)row * DD + tid + 256] = f2b(o1);
}

extern "C" void kernel_launch(void* const* d_in, const int* in_sizes, int n_in,
                              void* d_out, int out_size, void* d_ws,
                              size_t ws_size, hipStream_t stream) {
  const int* etype = (const int*)d_in[0];
  const float* etime = (const float*)d_in[1];
  const float* npm = (const float*)d_in[2];
  const float* emb = (const float*)d_in[3];
  const float* Wq = (const float*)d_in[4];
  const float* Wk = (const float*)d_in[5];
  const float* Wv = (const float*)d_in[6];
  const float* fc_w = (const float*)d_in[7];
  const float* fc_b = (const float*)d_in[8];
  const float* ln1_g = (const float*)d_in[9];
  const float* ln1_b = (const float*)d_in[10];
  const float* W1 = (const float*)d_in[11];
  const float* b1 = (const float*)d_in[12];
  const float* W2 = (const float*)d_in[13];
  const float* b2 = (const float*)d_in[14];
  const float* ln2_g = (const float*)d_in[15];
  const float* ln2_b = (const float*)d_in[16];

  float* x = (float*)d_out;
  char* ws = (char*)d_ws;
  const size_t SZF = (size_t)MM * DD * sizeof(float);
  const size_t SZB = (size_t)MM * DD * sizeof(short);
  float* tem = (float*)ws; ws += SZF;
  float* xa  = (float*)ws; ws += SZF;
  unsigned short* xab = (unsigned short*)ws; ws += SZB;
  unsigned short* xbf = (unsigned short*)ws; ws += SZB;
  unsigned short* qkv = (unsigned short*)ws; ws += (size_t)MM * 1536 * 2;
  unsigned short* vT  = (unsigned short*)ws; ws += (size_t)BB * NH * 64 * LL * 2;
  unsigned short* ao  = (unsigned short*)ws; ws += SZB;
  unsigned short* hb  = (unsigned short*)ws; ws += (size_t)MM * DINNER * 2;
  float* yb = (float*)ws; ws += SZF;
  unsigned short* qkvT = (unsigned short*)ws; ws += (size_t)NLAYERS * 1536 * 512 * 2;
  unsigned short* fcT  = (unsigned short*)ws; ws += (size_t)NLAYERS * 512 * 512 * 2;
  unsigned short* W1T  = (unsigned short*)ws; ws += (size_t)NLAYERS * 2048 * 512 * 2;
  unsigned short* W2T  = (unsigned short*)ws; ws += (size_t)NLAYERS * 512 * 2048 * 2;
  float* meanV = (float*)ws; ws += BB * NH * 64 * sizeof(float);

  init_kernel<<<MM, 512, 0, stream>>>(etype, etime, npm, emb, tem, x);

  wtrans_kernel<<<dim3(16, 16, NLAYERS), 256, 0, stream>>>(
      Wq, qkvT + 0 * 512 * 512, 512, 512, 512L * 512, 1536L * 512);
  wtrans_kernel<<<dim3(16, 16, NLAYERS), 256, 0, stream>>>(
      Wk, qkvT + 1 * 512 * 512, 512, 512, 512L * 512, 1536L * 512);
  wtrans_kernel<<<dim3(16, 16, NLAYERS), 256, 0, stream>>>(
      Wv, qkvT + 2 * 512 * 512, 512, 512, 512L * 512, 1536L * 512);
  wtrans_kernel<<<dim3(16, 16, NLAYERS), 256, 0, stream>>>(
      fc_w, fcT, 512, 512, 512L * 512, 512L * 512);
  wtrans_kernel<<<dim3(64, 16, NLAYERS), 256, 0, stream>>>(
      W1, W1T, 512, 2048, 512L * 2048, 2048L * 512);
  wtrans_kernel<<<dim3(16, 64, NLAYERS), 256, 0, stream>>>(
      W2, W2T, 2048, 512, 2048L * 512, 512L * 2048);

  for (int l = 0; l < NLAYERS; l++) {
    add_tem_kernel<<<(MM * DD / 4) / 256, 256, 0, stream>>>(
        (const float4*)x, (const float4*)tem, (float4*)xa, (us4*)xab);

    gemm_kernel<128, false, false, false, true><<<dim3(12, 64), 256, 0, stream>>>(
        xab, qkvT + (size_t)l * 1536 * 512, nullptr, nullptr, 0, qkv, 1536,
        MM, 1536, 512);

    vtrans_kernel<<<dim3(32, 32), 256, 0, stream>>>(qkv, vT);
    meanv_kernel<<<BB * NH, 256, 0, stream>>>(vT, meanV);
    attn_kernel<<<BB * NH * 32, 256, 0, stream>>>(qkv, vT, etype, meanV, ao);

    gemm_kernel<64, true, true, false, false><<<dim3(4, 128), 256, 0, stream>>>(
        ao, fcT + (size_t)l * 512 * 512, fc_b + (size_t)l * 512, xa, 512, yb,
        512, MM, 512, 512);
    ln_kernel<<<MM, 256, 0, stream>>>(yb, ln1_g + (size_t)l * 512,
                                      ln1_b + (size_t)l * 512, npm, x, xbf);

    gemm_kernel<128, true, false, true, true><<<dim3(16, 64), 256, 0, stream>>>(
        xbf, W1T + (size_t)l * 2048 * 512, b1 + (size_t)l * 2048, nullptr, 0,
        hb, 2048, MM, 2048, 512);
    gemm_kernel<64, true, true, false, false><<<dim3(4, 128), 256, 0, stream>>>(
        hb, W2T + (size_t)l * 512 * 2048, b2 + (size_t)l * 512, x, 512, yb,
        512, MM, 512, 2048);
    ln_kernel<<<MM, 256, 0, stream>>>(yb, ln2_g + (size_t)l * 512,
                                      ln2_b + (size_t)l * 512, npm, x, xbf);
  }
}

// Round 8
// 1113.520 us; speedup vs baseline: 1.3760x; 1.3760x over previous
//
#include <hip/hip_runtime.h>
#include <math.h>

#define BB 4
#define LL 2048
#define DD 512
#define NH 8
#define DINNER 2048
#define NLAYERS 4
#define MM (BB * LL)  // 8192

typedef __attribute__((ext_vector_type(8))) __bf16 bf16x8;
typedef __attribute__((ext_vector_type(4))) float f32x4;
typedef __attribute__((ext_vector_type(4))) unsigned short us4;

__device__ __forceinline__ unsigned short f2b(float f) {
  union { float f; unsigned u; } v; v.f = f;
  unsigned r = v.u + 0x7fffu + ((v.u >> 16) & 1u);
  return (unsigned short)(r >> 16);
}
__device__ __forceinline__ float b2f(unsigned short h) {
  union { unsigned u; float f; } v; v.u = ((unsigned)h) << 16; return v.f;
}

__device__ __forceinline__ void gload16(const void* g, void* l) {
  __builtin_amdgcn_global_load_lds(
      (const __attribute__((address_space(1))) void*)g,
      (__attribute__((address_space(3))) void*)l, 16, 0, 0);
}

// ---- init: temporal enc + embedding gather; emits xa = emb+tem directly ----
__global__ __launch_bounds__(512) void init_kernel(
    const int* __restrict__ etype, const float* __restrict__ etime,
    const float* __restrict__ npm, const float* __restrict__ emb,
    float* __restrict__ tem, float* __restrict__ xa,
    unsigned short* __restrict__ xab) {
  int row = blockIdx.x;
  int d = threadIdx.x;
  float t = etime[row];
  float mask = npm[row];
  int dd = d & ~1;
  float pv = expf(9.210340371976184f * ((float)dd * (1.0f / (float)DD)));
  float r = t / pv;
  float val = (d & 1) ? cosf(r) : sinf(r);
  float tv = val * mask;
  tem[(size_t)row * DD + d] = tv;
  int ty = etype[row];
  float a = emb[(size_t)ty * DD + d] + tv;
  xa[(size_t)row * DD + d] = a;
  xab[(size_t)row * DD + d] = f2b(a);
}

// ---------------- weight transpose+convert: fp32 [K][N] -> bf16 [N][K] ----
__global__ __launch_bounds__(256) void wtrans_kernel(
    const float* __restrict__ in, unsigned short* __restrict__ out,
    int K, int N, long in_ls, long out_ls) {
  __shared__ float t[32][33];
  int l = blockIdx.z;
  int n0 = blockIdx.x * 32, k0 = blockIdx.y * 32;
  int tx = threadIdx.x & 31, ty = threadIdx.x >> 5;
  const float* ip = in + (size_t)l * in_ls;
  unsigned short* op = out + (size_t)l * out_ls;
#pragma unroll
  for (int r = ty; r < 32; r += 8)
    t[r][tx] = ip[(size_t)(k0 + r) * N + n0 + tx];
  __syncthreads();
#pragma unroll
  for (int r = ty; r < 32; r += 8)
    op[(size_t)(n0 + r) * K + k0 + tx] = f2b(t[tx][r]);
}

// ---- MFMA GEMM, 2-phase pipelined: C = A(bf16 [M,K]) @ WT(bf16 [N,K])^T --
template <int BM, bool BIAS, bool RES, bool GELU_, bool OBF16>
__global__ __launch_bounds__(256) void gemm_kernel(
    const unsigned short* __restrict__ A, const unsigned short* __restrict__ WT,
    const float* __restrict__ bias, const float* __restrict__ res, int ldres,
    void* __restrict__ Cv, int ldc, int M, int N, int K) {
  __shared__ unsigned short As[2][BM * 32];
  __shared__ unsigned short Bs[2][128 * 32];
  constexpr int NT = (BM == 128) ? 4 : 2;
  int tid = threadIdx.x;
  int w = tid >> 6, l = tid & 63;
  int li = l & 15, g = l >> 4;
  int row0 = blockIdx.y * BM, col0 = blockIdx.x * 128;
  int wm = (BM == 128) ? (w & 1) * 64 : 0;
  int wnb = (BM == 128) ? (w >> 1) * 64 : w * 32;
  f32x4 acc[4][NT];
#pragma unroll
  for (int i = 0; i < 4; i++)
#pragma unroll
    for (int j = 0; j < NT; j++) acc[i][j] = (f32x4){0.f, 0.f, 0.f, 0.f};

  int lr = l >> 2;
  int lc = (l & 3) ^ (lr & 3);

  auto stage = [&](int bb, int kb) {
    int k0 = kb * 32;
    if (BM == 128) {
#pragma unroll
      for (int i = 0; i < 2; i++) {
        int ai = w * 2 + i;
        gload16(A + (size_t)(row0 + ai * 16 + lr) * K + k0 + lc * 8,
                &As[bb][ai * 512]);
        gload16(WT + (size_t)(col0 + ai * 16 + lr) * K + k0 + lc * 8,
                &Bs[bb][ai * 512]);
      }
    } else {
      gload16(A + (size_t)(row0 + w * 16 + lr) * K + k0 + lc * 8,
              &As[bb][w * 512]);
#pragma unroll
      for (int i = 0; i < 2; i++) {
        int bi = w * 2 + i;
        gload16(WT + (size_t)(col0 + bi * 16 + lr) * K + k0 + lc * 8,
                &Bs[bb][bi * 512]);
      }
    }
  };

  int nk = K >> 5;
  stage(0, 0);
  __syncthreads();
  int buf = 0;
  for (int kb = 0; kb < nk; kb++) {
    if (kb + 1 < nk) stage(buf ^ 1, kb + 1);
    bf16x8 af[4], bf_[NT];
#pragma unroll
    for (int mt = 0; mt < 4; mt++) {
      int r = wm + mt * 16 + li;
      af[mt] = *(const bf16x8*)&As[buf][r * 32 + ((g ^ (r & 3)) * 8)];
    }
#pragma unroll
    for (int nt = 0; nt < NT; nt++) {
      int r = wnb + nt * 16 + li;
      bf_[nt] = *(const bf16x8*)&Bs[buf][r * 32 + ((g ^ (r & 3)) * 8)];
    }
#pragma unroll
    for (int mt = 0; mt < 4; mt++)
#pragma unroll
      for (int nt = 0; nt < NT; nt++)
        acc[mt][nt] = __builtin_amdgcn_mfma_f32_16x16x32_bf16(
            af[mt], bf_[nt], acc[mt][nt], 0, 0, 0);
    __syncthreads();
    buf ^= 1;
  }
#pragma unroll
  for (int mt = 0; mt < 4; mt++) {
#pragma unroll
    for (int nt = 0; nt < NT; nt++) {
#pragma unroll
      for (int r = 0; r < 4; r++) {
        int row = row0 + wm + mt * 16 + g * 4 + r;
        int col = col0 + wnb + nt * 16 + li;
        float v = acc[mt][nt][r];
        if (BIAS) v += bias[col];
        if (RES) v += res[(size_t)row * ldres + col];
        if (GELU_) v = 0.5f * v * (1.0f + erff(v * 0.70710678118654752f));
        if (OBF16)
          ((unsigned short*)Cv)[(size_t)row * ldc + col] = f2b(v);
        else
          ((float*)Cv)[(size_t)row * ldc + col] = v;
      }
    }
  }
}

// ---------------- transpose v slice of qkv -> vT [bh*64+d][L] ----------
__global__ __launch_bounds__(256) void vtrans_kernel(
    const unsigned short* __restrict__ qkv, unsigned short* __restrict__ vT) {
  __shared__ unsigned short t[64][65];
  int bh = blockIdx.y;
  int b = bh >> 3, h = bh & 7;
  int l0 = blockIdx.x * 64;
  int tid = threadIdx.x;
  int c = tid & 63, p = tid >> 6;
#pragma unroll
  for (int r = p; r < 64; r += 4)
    t[r][c] = qkv[(size_t)(b * LL + l0 + r) * 1536 + 1024 + h * 64 + c];
  __syncthreads();
#pragma unroll
  for (int r = p; r < 64; r += 4)
    vT[((size_t)bh * 64 + r) * LL + l0 + c] = t[c][r];
}

// ---------------- meanV over L per (b,h,d), from vT ----------------
__global__ __launch_bounds__(256) void meanv_kernel(
    const unsigned short* __restrict__ vT, float* __restrict__ meanV) {
  __shared__ float red[256];
  int bh = blockIdx.x;
  int tid = threadIdx.x;
  int d = tid >> 2, p = tid & 3;
  const unsigned short* vp = vT + ((size_t)bh * 64 + d) * LL;
  float s = 0.f;
  for (int i = p * 512; i < p * 512 + 512; i++) s += b2f(vp[i]);
  red[tid] = s;
  __syncthreads();
  if (p == 0)
    meanV[bh * 64 + d] =
        (red[tid] + red[tid + 1] + red[tid + 2] + red[tid + 3]) *
        (1.0f / (float)LL);
}

// ---- MFMA flash attention, 2-way KEY-SPLIT (round-3 proven inner loop) ----
// Grid 2048 = 32 bh x 32 qt x 2 halves, LPT + XCD-chunked remap. Each block
// runs the identical KVBLK=64 loop over its half of the key-tiles and writes
// l-normalized bf16 partial O + (m,l). amerge_kernel combines the halves.
__global__ __launch_bounds__(256) void attn_kernel(
    const unsigned short* __restrict__ qkv, const unsigned short* __restrict__ vT,
    const int* __restrict__ etype, unsigned short* __restrict__ opart,
    float* __restrict__ ml) {
  __shared__ unsigned short Ks[2][64 * 64];  // [buf][key*64+d], swizzled 8KB
  __shared__ unsigned short Ps[64][72];
  int hwbid = blockIdx.x;
  int work = (hwbid & 7) * 256 + (hwbid >> 3);  // XCD-chunked (bijective)
  int bh = work >> 6;
  int rem = work & 63;
  int qt = 31 - (rem >> 1);  // LPT: big q-tiles first
  int half = rem & 1;
  int h = bh & 7, b = bh >> 3;
  int q0 = qt * 64;
  int nt = qt + 1;          // 64-key tiles in causal range
  int ha = (nt + 1) >> 1;   // A gets ceil(nt/2) (A always nonempty)
  int j0 = half ? ha : 0;
  int j1 = half ? nt : ha;
  int pidx = (bh * 32 + qt) * 2 + half;
  int tid = threadIdx.x, w = tid >> 6, l = tid & 63;
  int g = l >> 4, li = l & 15;

  f32x4 o[4];
#pragma unroll
  for (int n = 0; n < 4; n++) o[n] = (f32x4){0.f, 0.f, 0.f, 0.f};
  float mreg[4], lreg[4];
#pragma unroll
  for (int r = 0; r < 4; r++) { mreg[r] = -3.0e38f; lreg[r] = 0.f; }

  if (j0 < j1) {
    const unsigned short* qrp =
        qkv + (size_t)(b * LL + q0 + w * 16 + li) * 1536 + h * 64;
    bf16x8 aq0 = *(const bf16x8*)&qrp[g * 8];
    bf16x8 aq1 = *(const bf16x8*)&qrp[32 + g * 8];

    // prologue: stage tile j0 into buf 0
#pragma unroll
    for (int e = 0; e < 2; e++) {
      int idx = e * 256 + tid;
      int r = idx >> 3;
      int src = (l & 7) ^ (r & 7);
      gload16(
          qkv + (size_t)(b * LL + j0 * 64 + r) * 1536 + 512 + h * 64 + src * 8,
          &Ks[0][(e * 256 + w * 64) * 8]);
    }
    __syncthreads();

    int cur = 0;
    for (int j = j0; j < j1; j++) {
      int k0 = j << 6;
      if (j + 1 < j1) {
#pragma unroll
        for (int e = 0; e < 2; e++) {
          int idx = e * 256 + tid;
          int r = idx >> 3;
          int src = (l & 7) ^ (r & 7);
          gload16(qkv + (size_t)(b * LL + k0 + 64 + r) * 1536 + 512 + h * 64 +
                      src * 8,
                  &Ks[cur ^ 1][(e * 256 + w * 64) * 8]);
        }
      }
      // V frags + pad mask direct from global (L2-resident), issued early
      bf16x8 bv0[4], bv1[4];
      int kp4[4];
#pragma unroll
      for (int n = 0; n < 4; n++) {
        const unsigned short* vp =
            vT + ((size_t)(bh * 64 + n * 16 + li)) * LL + k0;
        bv0[n] = *(const bf16x8*)&vp[g * 8];
        bv1[n] = *(const bf16x8*)&vp[32 + g * 8];
        kp4[n] = etype[b * LL + k0 + n * 16 + li];
      }
      // S = Q K^T from swizzled LDS
      f32x4 s[4];
#pragma unroll
      for (int n = 0; n < 4; n++) {
        int rK = n * 16 + li;
        const unsigned short* kb = &Ks[cur][rK * 64];
        bf16x8 bk0 = *(const bf16x8*)&kb[(g ^ (rK & 7)) * 8];
        bf16x8 bk1 = *(const bf16x8*)&kb[((g + 4) ^ (rK & 7)) * 8];
        f32x4 a = (f32x4){0.f, 0.f, 0.f, 0.f};
        __builtin_amdgcn_s_setprio(1);
        a = __builtin_amdgcn_mfma_f32_16x16x32_bf16(aq0, bk0, a, 0, 0, 0);
        a = __builtin_amdgcn_mfma_f32_16x16x32_bf16(aq1, bk1, a, 0, 0, 0);
        __builtin_amdgcn_s_setprio(0);
        s[n] = a;
      }
      // scale + mask
#pragma unroll
      for (int n = 0; n < 4; n++) {
        int key = k0 + n * 16 + li;
        bool pad = (kp4[n] == 0);
#pragma unroll
        for (int r = 0; r < 4; r++) {
          int qrow = q0 + w * 16 + g * 4 + r;
          float sv = s[n][r] * 0.125f;
          if (key > qrow || pad) sv = -1.0e9f;
          s[n][r] = sv;
        }
      }
      // wave-parallel online softmax (reduce across 16 li lanes)
      float pm[4], corr[4], psum[4];
#pragma unroll
      for (int r = 0; r < 4; r++)
        pm[r] = fmaxf(fmaxf(s[0][r], s[1][r]), fmaxf(s[2][r], s[3][r]));
#pragma unroll
      for (int msk = 1; msk <= 8; msk <<= 1)
#pragma unroll
        for (int r = 0; r < 4; r++)
          pm[r] = fmaxf(pm[r], __shfl_xor(pm[r], msk, 64));
#pragma unroll
      for (int r = 0; r < 4; r++) {
        float mnew = fmaxf(mreg[r], pm[r]);
        corr[r] = __expf(mreg[r] - mnew);
        mreg[r] = mnew;
        float ps = 0.f;
#pragma unroll
        for (int n = 0; n < 4; n++) {
          float p = __expf(s[n][r] - mnew);
          s[n][r] = p;
          ps += p;
        }
        psum[r] = ps;
      }
#pragma unroll
      for (int msk = 1; msk <= 8; msk <<= 1)
#pragma unroll
        for (int r = 0; r < 4; r++) psum[r] += __shfl_xor(psum[r], msk, 64);
#pragma unroll
      for (int r = 0; r < 4; r++) lreg[r] = lreg[r] * corr[r] + psum[r];
      // P -> LDS (own-wave rows only; same-wave ordering via lgkmcnt)
#pragma unroll
      for (int n = 0; n < 4; n++)
#pragma unroll
        for (int r = 0; r < 4; r++)
          Ps[w * 16 + g * 4 + r][n * 16 + li] = f2b(s[n][r]);
      // rescale O
#pragma unroll
      for (int n = 0; n < 4; n++)
#pragma unroll
        for (int r = 0; r < 4; r++) o[n][r] *= corr[r];
      // PV: A = P rows (LDS), B = V frags (regs)
      bf16x8 ap0 = *(const bf16x8*)&Ps[w * 16 + li][g * 8];
      bf16x8 ap1 = *(const bf16x8*)&Ps[w * 16 + li][32 + g * 8];
      __builtin_amdgcn_s_setprio(1);
#pragma unroll
      for (int n = 0; n < 4; n++) {
        o[n] = __builtin_amdgcn_mfma_f32_16x16x32_bf16(ap0, bv0[n], o[n], 0, 0, 0);
        o[n] = __builtin_amdgcn_mfma_f32_16x16x32_bf16(ap1, bv1[n], o[n], 0, 0, 0);
      }
      __builtin_amdgcn_s_setprio(0);
      __syncthreads();  // drains prefetch (vmcnt) + Ks/Ps traffic
      cur ^= 1;
    }
  }
  // epilogue: l-normalized partial O (bf16) + per-row (m,l)
#pragma unroll
  for (int r = 0; r < 4; r++) {
    int qrl = w * 16 + g * 4 + r;
    float inv = (lreg[r] > 0.f) ? 1.0f / lreg[r] : 0.f;
#pragma unroll
    for (int n = 0; n < 4; n++)
      opart[((size_t)pidx * 64 + qrl) * 64 + n * 16 + li] = f2b(o[n][r] * inv);
    if (li == 0) {
      ml[(size_t)pidx * 128 + qrl] = mreg[r];
      ml[(size_t)pidx * 128 + 64 + qrl] = lreg[r];
    }
  }
}

// ---------------- merge the two key-split halves ----------------
__global__ __launch_bounds__(256) void amerge_kernel(
    const unsigned short* __restrict__ opart, const float* __restrict__ ml,
    const float* __restrict__ meanV, unsigned short* __restrict__ ao) {
  int blk = blockIdx.x;  // bh*32 + qt  (1024 blocks)
  int bh = blk >> 5, qt = blk & 31;
  int b = bh >> 3, h = bh & 7;
  int tid = threadIdx.x;
  int d = tid & 63;
  int pA = blk * 2, pB = blk * 2 + 1;
  for (int rr = tid >> 6; rr < 64; rr += 4) {
    float mA = ml[(size_t)pA * 128 + rr], lA = ml[(size_t)pA * 128 + 64 + rr];
    float mB = ml[(size_t)pB * 128 + rr], lB = ml[(size_t)pB * 128 + 64 + rr];
    float m = fmaxf(mA, mB);
    float v;
    if (m <= -1.0e8f) {
      v = meanV[bh * 64 + d];  // fully-masked row: uniform softmax = meanV
    } else {
      float acc = 0.f, wsum = 0.f;
      if (lA > 0.f) {
        float wA = __expf(mA - m) * lA;
        acc += b2f(opart[((size_t)pA * 64 + rr) * 64 + d]) * wA;
        wsum += wA;
      }
      if (lB > 0.f) {
        float wB = __expf(mB - m) * lB;
        acc += b2f(opart[((size_t)pB * 64 + rr) * 64 + d]) * wB;
        wsum += wB;
      }
      v = acc / wsum;
    }
    int qr = qt * 64 + rr;
    ao[(size_t)(b * LL + qr) * DD + h * 64 + d] = f2b(v);
  }
}

// ---------------- LayerNorm (+npm); ADDTEM also emits xa=x+tem ----------
template <bool ADDTEM>
__global__ __launch_bounds__(256) void ln_kernel(
    const float* __restrict__ in, const float* __restrict__ g,
    const float* __restrict__ bta, const float* __restrict__ npm,
    const float* __restrict__ tem, float* __restrict__ out,
    float* __restrict__ out2, unsigned short* __restrict__ out_bf) {
  __shared__ float red[4];
  int row = blockIdx.x;
  int tid = threadIdx.x;
  const float* rp = in + (size_t)row * DD;
  float v0 = rp[tid], v1 = rp[tid + 256];
  float s = v0 + v1;
#pragma unroll
  for (int o = 32; o > 0; o >>= 1) s += __shfl_down(s, o, 64);
  if ((tid & 63) == 0) red[tid >> 6] = s;
  __syncthreads();
  float mean = (red[0] + red[1] + red[2] + red[3]) * (1.0f / (float)DD);
  float d0 = v0 - mean, d1 = v1 - mean;
  float sq = d0 * d0 + d1 * d1;
#pragma unroll
  for (int o = 32; o > 0; o >>= 1) sq += __shfl_down(sq, o, 64);
  __syncthreads();
  if ((tid & 63) == 0) red[tid >> 6] = sq;
  __syncthreads();
  float var = (red[0] + red[1] + red[2] + red[3]) * (1.0f / (float)DD);
  float rstd = rsqrtf(var + 1e-6f);
  float m = npm[row];
  float o0 = (d0 * rstd * g[tid] + bta[tid]) * m;
  float o1 = (d1 * rstd * g[tid + 256] + bta[tid + 256]) * m;
  out[(size_t)row * DD + tid] = o0;
  out[(size_t)row * DD + tid + 256] = o1;
  if (ADDTEM) {
    float a0 = o0 + tem[(size_t)row * DD + tid];
    float a1 = o1 + tem[(size_t)row * DD + tid + 256];
    out2[(size_t)row * DD + tid] = a0;
    out2[(size_t)row * DD + tid + 256] = a1;
    out_bf[(size_t)row * DD + tid] = f2b(a0);
    out_bf[(size_t)row * DD + tid + 256] = f2b(a1);
  } else {
    out_bf[(size_t)row * DD + tid] = f2b(o0);
    out_bf[(size_t)row * DD + tid + 256] = f2b(o1);
  }
}

extern "C" void kernel_launch(void* const* d_in, const int* in_sizes, int n_in,
                              void* d_out, int out_size, void* d_ws,
                              size_t ws_size, hipStream_t stream) {
  const int* etype = (const int*)d_in[0];
  const float* etime = (const float*)d_in[1];
  const float* npm = (const float*)d_in[2];
  const float* emb = (const float*)d_in[3];
  const float* Wq = (const float*)d_in[4];
  const float* Wk = (const float*)d_in[5];
  const float* Wv = (const float*)d_in[6];
  const float* fc_w = (const float*)d_in[7];
  const float* fc_b = (const float*)d_in[8];
  const float* ln1_g = (const float*)d_in[9];
  const float* ln1_b = (const float*)d_in[10];
  const float* W1 = (const float*)d_in[11];
  const float* b1 = (const float*)d_in[12];
  const float* W2 = (const float*)d_in[13];
  const float* b2 = (const float*)d_in[14];
  const float* ln2_g = (const float*)d_in[15];
  const float* ln2_b = (const float*)d_in[16];

  float* x = (float*)d_out;
  char* ws = (char*)d_ws;
  const size_t SZF = (size_t)MM * DD * sizeof(float);
  const size_t SZB = (size_t)MM * DD * sizeof(short);
  float* tem = (float*)ws; ws += SZF;
  float* xa  = (float*)ws; ws += SZF;
  unsigned short* xab = (unsigned short*)ws; ws += SZB;
  unsigned short* xbf = (unsigned short*)ws; ws += SZB;
  unsigned short* qkv = (unsigned short*)ws; ws += (size_t)MM * 1536 * 2;
  unsigned short* vT  = (unsigned short*)ws; ws += (size_t)BB * NH * 64 * LL * 2;
  unsigned short* ao  = (unsigned short*)ws; ws += SZB;
  unsigned short* hb  = (unsigned short*)ws; ws += (size_t)MM * DINNER * 2;
  float* yb = (float*)ws; ws += SZF;
  unsigned short* qkvT = (unsigned short*)ws; ws += (size_t)NLAYERS * 1536 * 512 * 2;
  unsigned short* fcT  = (unsigned short*)ws; ws += (size_t)NLAYERS * 512 * 512 * 2;
  unsigned short* W1T  = (unsigned short*)ws; ws += (size_t)NLAYERS * 2048 * 512 * 2;
  unsigned short* W2T  = (unsigned short*)ws; ws += (size_t)NLAYERS * 512 * 2048 * 2;
  float* meanV = (float*)ws; ws += BB * NH * 64 * sizeof(float);
  unsigned short* opart = (unsigned short*)ws; ws += (size_t)2048 * 64 * 64 * 2;
  float* ml = (float*)ws; ws += (size_t)2048 * 128 * sizeof(float);

  init_kernel<<<MM, 512, 0, stream>>>(etype, etime, npm, emb, tem, xa, xab);

  wtrans_kernel<<<dim3(16, 16, NLAYERS), 256, 0, stream>>>(
      Wq, qkvT + 0 * 512 * 512, 512, 512, 512L * 512, 1536L * 512);
  wtrans_kernel<<<dim3(16, 16, NLAYERS), 256, 0, stream>>>(
      Wk, qkvT + 1 * 512 * 512, 512, 512, 512L * 512, 1536L * 512);
  wtrans_kernel<<<dim3(16, 16, NLAYERS), 256, 0, stream>>>(
      Wv, qkvT + 2 * 512 * 512, 512, 512, 512L * 512, 1536L * 512);
  wtrans_kernel<<<dim3(16, 16, NLAYERS), 256, 0, stream>>>(
      fc_w, fcT, 512, 512, 512L * 512, 512L * 512);
  wtrans_kernel<<<dim3(64, 16, NLAYERS), 256, 0, stream>>>(
      W1, W1T, 512, 2048, 512L * 2048, 2048L * 512);
  wtrans_kernel<<<dim3(16, 64, NLAYERS), 256, 0, stream>>>(
      W2, W2T, 2048, 512, 2048L * 512, 512L * 2048);

  for (int l = 0; l < NLAYERS; l++) {
    gemm_kernel<128, false, false, false, true><<<dim3(12, 64), 256, 0, stream>>>(
        xab, qkvT + (size_t)l * 1536 * 512, nullptr, nullptr, 0, qkv, 1536,
        MM, 1536, 512);

    vtrans_kernel<<<dim3(32, 32), 256, 0, stream>>>(qkv, vT);
    meanv_kernel<<<BB * NH, 256, 0, stream>>>(vT, meanV);
    attn_kernel<<<2048, 256, 0, stream>>>(qkv, vT, etype, opart, ml);
    amerge_kernel<<<1024, 256, 0, stream>>>(opart, ml, meanV, ao);

    gemm_kernel<64, true, true, false, false><<<dim3(4, 128), 256, 0, stream>>>(
        ao, fcT + (size_t)l * 512 * 512, fc_b + (size_t)l * 512, xa, 512, yb,
        512, MM, 512, 512);
    ln_kernel<false><<<MM, 256, 0, stream>>>(
        yb, ln1_g + (size_t)l * 512, ln1_b + (size_t)l * 512, npm, nullptr, x,
        nullptr, xbf);

    gemm_kernel<128, true, false, true, true><<<dim3(16, 64), 256, 0, stream>>>(
        xbf, W1T + (size_t)l * 2048 * 512, b1 + (size_t)l * 2048, nullptr, 0,
        hb, 2048, MM, 2048, 512);
    gemm_kernel<64, true, true, false, false><<<dim3(4, 128), 256, 0, stream>>>(
        hb, W2T + (size_t)l * 512 * 2048, b2 + (size_t)l * 512, x, 512, yb,
        512, MM, 512, 2048);
    ln_kernel<true><<<MM, 256, 0, stream>>>(
        yb, ln2_g + (size_t)l * 512, ln2_b + (size_t)l * 512, npm, tem, x, xa,
        xab);
  }
}